// Round 1
// baseline (397.754 us; speedup 1.0000x reference)
//
#include <hip/hip_runtime.h>

#define N_NODES 50000
#define N_EDGES 800000
#define CH 128
#define N_GRAPHS 128
#define N_LAYERS 3
#define OUT_CH 16
#define BN_EPS 1e-5f
#define NSPLIT 32
#define NB 196            // dst>>8 buckets (256 dsts each)
#define BCAP 4608
#define EPB 4096
#define NTILES (N_NODES / 16)      // 3125 exact
#define SSTRIDE 20
#define NPASS 4            // channel-split passes: 32 ch (64B) per pass -> 3.2MB slice, L2-resident
// setup_kernel block partition
#define CB 6250            // cast blocks (1.6M float4 / 256)
#define SB 196             // starts blocks
#define PB 388             // prep blocks

typedef unsigned short ushort_t;
typedef __attribute__((ext_vector_type(8))) short bf16x8;
typedef __attribute__((ext_vector_type(4))) float f32x4;

__device__ inline ushort_t f2b(float f) {
    unsigned u = __float_as_uint(f);
    unsigned r = (u + 0x7fffu + ((u >> 16) & 1u)) >> 16;
    return (ushort_t)r;
}
__device__ inline float b2f(ushort_t b) { return __uint_as_float((unsigned)b << 16); }
__device__ inline float blo(unsigned u) { return __uint_as_float(u << 16); }
__device__ inline float bhi(unsigned u) { return __uint_as_float(u & 0xffff0000u); }

// ---------------- merged setup: cast | starts+pooled-zero | weight/epilogue prep ----------
__global__ __launch_bounds__(256) void setup_kernel(
    const float4* __restrict__ x, ushort4* __restrict__ xb, int* __restrict__ gcur,
    const int* __restrict__ batch, int* __restrict__ starts, float* __restrict__ pooled,
    const float* __restrict__ W1, const float* __restrict__ W2, ushort_t* __restrict__ Wt,
    const float* __restrict__ b1, const float* __restrict__ b2,
    const float* __restrict__ gamma, const float* __restrict__ beta,
    const float* __restrict__ mean, const float* __restrict__ var,
    float* __restrict__ scale, float* __restrict__ shift) {
    int bid = blockIdx.x, t = threadIdx.x;
    if (bid < CB) {
        // ---- cast fp32 -> bf16 flat [N][128]; zero gcur ----
        int i = bid * 256 + t;
        if (i < NB) gcur[i] = 0;
        float4 v = x[i];               // CB*256 == n4 exactly
        ushort4 o;
        o.x = f2b(v.x); o.y = f2b(v.y); o.z = f2b(v.z); o.w = f2b(v.w);
        xb[i] = o;
    } else if (bid < CB + SB) {
        // ---- graph starts from sorted batch; zero pooled ----
        int i = (bid - CB) * 256 + t;
        if (i < N_GRAPHS * CH) pooled[i] = 0.f;
        if (i >= N_NODES) return;
        int b = batch[i];
        if (i == 0) {
            for (int g = 0; g <= b; ++g) starts[g] = 0;
        } else {
            int pb = batch[i - 1];
            for (int g = pb + 1; g <= b; ++g) starts[g] = i;
        }
        if (i == N_NODES - 1) {
            for (int g = b + 1; g <= N_GRAPHS; ++g) starts[g] = N_NODES;
        }
    } else {
        // ---- weight fragments [ct][ks][lane][j] + scale/shift ----
        int i = (bid - CB - SB) * 256 + t;
        if (i < 6 * CH * CH) {
            int mat = i >> 14, r = i & 16383;
            int j = r & 7, bb = r >> 3;
            int lane = bb & 63, cs = bb >> 6;
            int ct = cs >> 2, ks = cs & 3;
            int n = ct * 16 + (lane & 15);
            int k = ks * 32 + (lane >> 4) * 8 + j;
            const float* Wsrc = (mat < 3) ? (W1 + (size_t)mat * CH * CH)
                                          : (W2 + (size_t)(mat - 3) * CH * CH);
            Wt[i] = f2b(Wsrc[k * CH + n]);
        } else {
            int e = i - 6 * CH * CH;
            if (e >= 6 * CH) return;
            int mat = e / CH, c = e % CH;
            if (mat < 3) {
                scale[e] = 1.f;
                shift[e] = b1[mat * CH + c];
            } else {
                int l = mat - 3;
                float inv = gamma[l * CH + c] * rsqrtf(var[l * CH + c] + BN_EPS);
                scale[e] = inv;
                shift[e] = (b2[l * CH + c] - mean[l * CH + c]) * inv + beta[l * CH + c];
            }
        }
    }
}

// ---------------- edge binning: pack = src | (dst&255)<<16, bucket = dst>>8 ----------------
__global__ __launch_bounds__(256) void bin_kernel(const int* __restrict__ src,
                                                  const int* __restrict__ dst,
                                                  int* __restrict__ gcur,
                                                  unsigned* __restrict__ gbuck) {
    __shared__ int lcnt[256];
    __shared__ int lpref[256];
    __shared__ int lpos[NB];
    __shared__ int lbase[NB];
    __shared__ unsigned stage[EPB];
    __shared__ unsigned char sbk[EPB];
    int t = threadIdx.x;
    int e0 = blockIdx.x * EPB;
    int nloc = N_EDGES - e0; if (nloc > EPB) nloc = EPB;

    lcnt[t] = 0;
    __syncthreads();

    int2 ed[16];
    #pragma unroll
    for (int j = 0; j < 16; ++j) {
        int i = j * 256 + t;
        if (i < nloc) {
            ed[j].x = src[e0 + i];
            ed[j].y = dst[e0 + i];
            atomicAdd(&lcnt[ed[j].y >> 8], 1);
        } else ed[j].y = -1;
    }
    __syncthreads();
    int v = lcnt[t];
    lpref[t] = v;
    __syncthreads();
    for (int off = 1; off < 256; off <<= 1) {
        int y = (t >= off) ? lpref[t - off] : 0;
        __syncthreads();
        lpref[t] += y;
        __syncthreads();
    }
    int excl = lpref[t] - v;
    __syncthreads();
    lpref[t] = excl;
    if (t < NB) {
        lpos[t] = excl;
        lbase[t] = atomicAdd(&gcur[t], v);
    }
    __syncthreads();
    #pragma unroll
    for (int j = 0; j < 16; ++j) {
        if (ed[j].y >= 0) {
            int b = ed[j].y >> 8;
            int slot = atomicAdd(&lpos[b], 1);
            stage[slot] = (unsigned)ed[j].x | ((unsigned)(ed[j].y & 255) << 16);
            sbk[slot] = (unsigned char)b;
        }
    }
    __syncthreads();
    for (int i = t; i < nloc; i += 256) {
        int b = sbk[i];
        gbuck[(size_t)b * BCAP + lbase[b] + (i - lpref[b])] = stage[i];
    }
}

// ---------------- per-bucket sort to CSR slots; inline bucket scan; writes rowptr ----------
__global__ __launch_bounds__(256) void place_kernel(const int* __restrict__ gcur,
                                                    const unsigned* __restrict__ gbuck,
                                                    int* __restrict__ rowptr,
                                                    ushort_t* __restrict__ esrc) {
    __shared__ ushort_t ssrc[BCAP];
    __shared__ unsigned char sd[BCAP];
    __shared__ int outS[BCAP];
    __shared__ int cnt[256], pref[256], cur[256];
    __shared__ int sscan[256];
    int b = blockIdx.x, t = threadIdx.x;
    // inline exclusive scan over all bucket sizes -> this bucket's base
    int gv = (t < NB) ? gcur[t] : 0;
    sscan[t] = gv;
    cnt[t] = 0;
    __syncthreads();
    for (int off = 1; off < 256; off <<= 1) {
        int y = (t >= off) ? sscan[t - off] : 0;
        __syncthreads();
        sscan[t] += y;
        __syncthreads();
    }
    int nb = gcur[b];
    int base = sscan[b] - nb;   // exclusive prefix
    for (int i = t; i < nb; i += 256) {
        unsigned p = gbuck[(size_t)b * BCAP + i];
        ssrc[i] = (ushort_t)(p & 0xffffu);
        int dl = (p >> 16) & 0xff;
        sd[i] = (unsigned char)dl;
        atomicAdd(&cnt[dl], 1);
    }
    __syncthreads();
    int v = cnt[t];
    pref[t] = v;
    __syncthreads();
    for (int off = 1; off < 256; off <<= 1) {
        int y = (t >= off) ? pref[t - off] : 0;
        __syncthreads();
        pref[t] += y;
        __syncthreads();
    }
    int excl = pref[t] - v;
    __syncthreads();
    pref[t] = excl;
    cur[t] = 0;
    int idx = (b << 8) + t;
    if (idx < N_NODES) rowptr[idx] = base + excl;
    if (b == NB - 1 && t == 0) rowptr[N_NODES] = N_EDGES;
    __syncthreads();
    for (int i = t; i < nb; i += 256) {
        int dl = sd[i];
        int p = pref[dl] + atomicAdd(&cur[dl], 1);
        outS[p] = ssrc[i];
    }
    __syncthreads();
    for (int i = t; i < nb; i += 256)
        esrc[base + i] = (ushort_t)outS[i];
}

// ---------------- aggregation: 4-pass channel split (32ch = 64B slices, L2-resident) -------
// pass = slow block index so concurrently-resident blocks share one 3.2MB h-slice per XCD L2.
// wave = one node; 4 edges/step, 16 lanes x 4B = one aligned 64B segment per edge gather.
__global__ __launch_bounds__(256) void agg_kernel(const unsigned* __restrict__ h2,
                                                  const int* __restrict__ rowptr,
                                                  const ushort_t* __restrict__ esrc,
                                                  unsigned* __restrict__ z2) {
    int lane = threadIdx.x & 63;
    int e4 = lane >> 4, l16 = lane & 15;
    int pass = blockIdx.x / (N_NODES / 4);
    int node = (blockIdx.x % (N_NODES / 4)) * 4 + (threadIdx.x >> 6);
    int cofs = pass * 16 + l16;                 // dword offset within the 64-dword row
    const unsigned* hrow = h2 + cofs;
    int e = rowptr[node], end = rowptr[node + 1];
    float ax = 0.f, ay = 0.f;
    for (; e + 16 <= end; e += 16) {
        int s0 = esrc[e + e4];
        int s1 = esrc[e + 4 + e4];
        int s2 = esrc[e + 8 + e4];
        int s3 = esrc[e + 12 + e4];
        unsigned u0 = hrow[(size_t)s0 * 64];
        unsigned u1 = hrow[(size_t)s1 * 64];
        unsigned u2 = hrow[(size_t)s2 * 64];
        unsigned u3 = hrow[(size_t)s3 * 64];
        ax += blo(u0) + blo(u1) + blo(u2) + blo(u3);
        ay += bhi(u0) + bhi(u1) + bhi(u2) + bhi(u3);
    }
    for (; e + 8 <= end; e += 8) {
        int s0 = esrc[e + e4];
        int s1 = esrc[e + 4 + e4];
        unsigned u0 = hrow[(size_t)s0 * 64];
        unsigned u1 = hrow[(size_t)s1 * 64];
        ax += blo(u0) + blo(u1);
        ay += bhi(u0) + bhi(u1);
    }
    for (; e + 4 <= end; e += 4) {
        unsigned u0 = hrow[(size_t)esrc[e + e4] * 64];
        ax += blo(u0); ay += bhi(u0);
    }
    if (e + e4 < end) {
        unsigned u0 = hrow[(size_t)esrc[e + e4] * 64];
        ax += blo(u0); ay += bhi(u0);
    }
    // reduce the 4 edge-groups (lanes l16, l16+16, l16+32, l16+48)
    ax += __shfl_xor(ax, 16); ay += __shfl_xor(ay, 16);
    ax += __shfl_xor(ax, 32); ay += __shfl_xor(ay, 32);
    if (e4 == 0) {
        unsigned self = hrow[(size_t)node * 64];
        ax += blo(self); ay += bhi(self);
        unsigned o = ((unsigned)f2b(ay) << 16) | (unsigned)f2b(ax);
        // NT store: don't evict the resident h-slice with z write lines
        __builtin_nontemporal_store(o, &z2[(size_t)node * 64 + cofs]);
    }
}

// ---------------- fused MLP (R8 conflict-free form) ----------------
__global__ __launch_bounds__(512) void mlp_kernel(const ushort_t* __restrict__ A,
                                                  const ushort_t* __restrict__ Wf1,
                                                  const ushort_t* __restrict__ Wf2,
                                                  const float* __restrict__ shift1,
                                                  const float* __restrict__ scale2,
                                                  const float* __restrict__ shift2,
                                                  ushort_t* __restrict__ Out) {
    __shared__ ushort_t sW1[CH * CH];
    __shared__ ushort_t sW2[CH * CH];
    __shared__ ushort_t sS[8][CH * SSTRIDE];

    int t = threadIdx.x;
    int wave = t >> 6, lane = t & 63;
    int quad = lane >> 4, l16 = lane & 15;

    {
        const uint4* g1 = (const uint4*)Wf1;
        const uint4* g2 = (const uint4*)Wf2;
        uint4* s1 = (uint4*)sW1;
        uint4* s2 = (uint4*)sW2;
        for (int i = t; i < 2048; i += 512) { s1[i] = g1[i]; s2[i] = g2[i]; }
    }
    __syncthreads();

    const bf16x8* w1f = (const bf16x8*)sW1;
    const bf16x8* w2f = (const bf16x8*)sW2;
    int wg = blockIdx.x * 8 + wave;

    for (int it = 0; it < 2; ++it) {
        int tile = wg + 2048 * it;
        if (tile >= NTILES) break;
        int arow = tile * 16 + l16;

        bf16x8 af[4];
        #pragma unroll
        for (int ks = 0; ks < 4; ++ks)
            af[ks] = *(const bf16x8*)(A + (size_t)arow * CH + ks * 32 + quad * 8);

        f32x4 acc[8];
        #pragma unroll
        for (int ct = 0; ct < 8; ++ct) acc[ct] = (f32x4){0.f, 0.f, 0.f, 0.f};
        #pragma unroll
        for (int ct = 0; ct < 8; ++ct)
            #pragma unroll
            for (int ks = 0; ks < 4; ++ks)
                acc[ct] = __builtin_amdgcn_mfma_f32_16x16x32_bf16(
                    af[ks], w1f[(ct * 4 + ks) * 64 + lane], acc[ct], 0, 0, 0);

        #pragma unroll
        for (int ct = 0; ct < 8; ++ct) {
            int k = ct * 16 + l16;
            float sh = shift1[k];
            uint2 p;
            p.x = ((unsigned)f2b(fmaxf(acc[ct][1] + sh, 0.f)) << 16)
                |  (unsigned)f2b(fmaxf(acc[ct][0] + sh, 0.f));
            p.y = ((unsigned)f2b(fmaxf(acc[ct][3] + sh, 0.f)) << 16)
                |  (unsigned)f2b(fmaxf(acc[ct][2] + sh, 0.f));
            *(uint2*)&sS[wave][k * SSTRIDE + quad * 4] = p;
        }

        bf16x8 af2[4];
        #pragma unroll
        for (int ks = 0; ks < 4; ++ks)
            #pragma unroll
            for (int j = 0; j < 8; ++j)
                af2[ks][j] = (short)sS[wave][(ks * 32 + quad * 8 + j) * SSTRIDE + l16];

        f32x4 acc2[8];
        #pragma unroll
        for (int ct = 0; ct < 8; ++ct) acc2[ct] = (f32x4){0.f, 0.f, 0.f, 0.f};
        #pragma unroll
        for (int ct = 0; ct < 8; ++ct)
            #pragma unroll
            for (int ks = 0; ks < 4; ++ks)
                acc2[ct] = __builtin_amdgcn_mfma_f32_16x16x32_bf16(
                    af2[ks], w2f[(ct * 4 + ks) * 64 + lane], acc2[ct], 0, 0, 0);

        int row0 = tile * 16;
        #pragma unroll
        for (int ct = 0; ct < 8; ++ct) {
            int col = ct * 16 + l16;
            float sc = scale2[col], sh = shift2[col];
            #pragma unroll
            for (int r = 0; r < 4; ++r) {
                int row = row0 + quad * 4 + r;
                Out[(size_t)row * CH + col] = f2b(fmaxf(acc2[ct][r] * sc + sh, 0.f));
            }
        }
    }
}

// ---------------- pooling (dword reads, 32 splits) + classifier ----------------
__global__ __launch_bounds__(64) void pool_kernel(const unsigned* __restrict__ h2,
                                                  const int* __restrict__ starts,
                                                  float* __restrict__ pooled) {
    int g = blockIdx.x / NSPLIT, s = blockIdx.x % NSPLIT;
    int c = threadIdx.x;
    int beg = starts[g], end = starts[g + 1];
    float s0 = 0.f, s1 = 0.f;
    for (int n = beg + s; n < end; n += NSPLIT) {
        unsigned u = h2[(size_t)n * 64 + c];
        s0 += blo(u); s1 += bhi(u);
    }
    atomicAdd(&pooled[g * CH + 2 * c], s0);
    atomicAdd(&pooled[g * CH + 2 * c + 1], s1);
}

__global__ __launch_bounds__(256) void cls_kernel(const float* __restrict__ pooled,
                                                  const float* __restrict__ Wc,
                                                  const float* __restrict__ bc,
                                                  float* __restrict__ out) {
    int i = blockIdx.x * blockDim.x + threadIdx.x;
    if (i >= N_GRAPHS * OUT_CH) return;
    int g = i / OUT_CH, o = i % OUT_CH;
    float s = bc[o];
    for (int k = 0; k < CH; ++k) s += pooled[g * CH + k] * Wc[k * OUT_CH + o];
    out[i] = s;
}

// ---------------- launch ----------------
extern "C" void kernel_launch(void* const* d_in, const int* in_sizes, int n_in,
                              void* d_out, int out_size, void* d_ws, size_t ws_size,
                              hipStream_t stream) {
    const float* x     = (const float*)d_in[0];
    const int*   eidx  = (const int*)d_in[1];
    const int*   batch = (const int*)d_in[2];
    const float* W1    = (const float*)d_in[3];
    const float* b1    = (const float*)d_in[4];
    const float* W2    = (const float*)d_in[5];
    const float* b2    = (const float*)d_in[6];
    const float* gamma = (const float*)d_in[7];
    const float* beta  = (const float*)d_in[8];
    const float* mean  = (const float*)d_in[9];
    const float* var   = (const float*)d_in[10];
    const float* Wc    = (const float*)d_in[11];
    const float* bc    = (const float*)d_in[12];
    float* out = (float*)d_out;

    const int* src = eidx;
    const int* dst = eidx + N_EDGES;

    char* w = (char*)d_ws;
    size_t off = 0;
    auto alloc = [&](size_t bytes) { void* p = w + off; off += (bytes + 255) & ~(size_t)255; return p; };
    int*      gcur   = (int*)alloc(NB * 4);
    unsigned* gbuck  = (unsigned*)alloc((size_t)NB * BCAP * 4);
    int*      rowptr = (int*)alloc((N_NODES + 1) * 4);
    ushort_t* esrc   = (ushort_t*)alloc(N_EDGES * 2);
    int*      starts = (int*)alloc((N_GRAPHS + 1) * 4);
    ushort_t* Bh     = (ushort_t*)alloc((size_t)N_NODES * CH * 2);
    ushort_t* Bz     = (ushort_t*)alloc((size_t)N_NODES * CH * 2);
    ushort_t* Wt     = (ushort_t*)alloc((size_t)6 * CH * CH * 2);
    float*    scale  = (float*)alloc(6 * CH * 4);
    float*    shift  = (float*)alloc(6 * CH * 4);
    float*    pooled = (float*)alloc(N_GRAPHS * CH * 4);
    (void)ws_size; (void)n_in; (void)in_sizes; (void)out_size;

    setup_kernel<<<CB + SB + PB, 256, 0, stream>>>(
        (const float4*)x, (ushort4*)Bh, gcur,
        batch, starts, pooled,
        W1, W2, Wt, b1, b2, gamma, beta, mean, var, scale, shift);
    bin_kernel<<<(N_EDGES + EPB - 1) / EPB, 256, 0, stream>>>(src, dst, gcur, gbuck);
    place_kernel<<<NB, 256, 0, stream>>>(gcur, gbuck, rowptr, esrc);

    const int agg_grid = NPASS * (N_NODES / 4);   // pass-major: 4 x 12500 blocks

    for (int i = 0; i < N_LAYERS; ++i) {
        agg_kernel<<<agg_grid, 256, 0, stream>>>((const unsigned*)Bh, rowptr, esrc,
                                                 (unsigned*)Bz);
        mlp_kernel<<<256, 512, 0, stream>>>(Bz,
                                            Wt + (size_t)i * CH * CH,
                                            Wt + (size_t)(3 + i) * CH * CH,
                                            shift + i * CH,
                                            scale + (3 + i) * CH,
                                            shift + (3 + i) * CH,
                                            Bh);
    }

    pool_kernel<<<N_GRAPHS * NSPLIT, 64, 0, stream>>>((const unsigned*)Bh, starts, pooled);
    cls_kernel<<<(N_GRAPHS * OUT_CH + 255) / 256, 256, 0, stream>>>(pooled, Wc, bc, out);
}

// Round 2
// 291.456 us; speedup vs baseline: 1.3647x; 1.3647x over previous
//
#include <hip/hip_runtime.h>

#define N_NODES 50000
#define N_EDGES 800000
#define CH 128
#define N_GRAPHS 128
#define N_LAYERS 3
#define OUT_CH 16
#define BN_EPS 1e-5f
#define NSPLIT 32
#define NB 196            // dst>>8 buckets (256 dsts each)
#define BCAP 4608
#define EPB 4096
#define NTILES (N_NODES / 16)      // 3125 exact
#define SSTRIDE 20
// setup_kernel block partition
#define CB 6250            // cast blocks (1.6M float4 / 256)
#define SB 196             // starts blocks
#define PB 388             // prep blocks

typedef unsigned short ushort_t;
typedef __attribute__((ext_vector_type(8))) short bf16x8;
typedef __attribute__((ext_vector_type(4))) float f32x4;
typedef __attribute__((ext_vector_type(2))) unsigned u32x2;

__device__ inline ushort_t f2b(float f) {
    unsigned u = __float_as_uint(f);
    unsigned r = (u + 0x7fffu + ((u >> 16) & 1u)) >> 16;
    return (ushort_t)r;
}
__device__ inline float blo(unsigned u) { return __uint_as_float(u << 16); }
__device__ inline float bhi(unsigned u) { return __uint_as_float(u & 0xffff0000u); }

// ---------------- merged setup: cast | starts+out-init | weight/epilogue prep ----------
__global__ __launch_bounds__(256) void setup_kernel(
    const float4* __restrict__ x, ushort4* __restrict__ xb, int* __restrict__ gcur,
    const int* __restrict__ batch, int* __restrict__ starts, float* __restrict__ outinit,
    const float* __restrict__ bc,
    const float* __restrict__ W1, const float* __restrict__ W2, ushort_t* __restrict__ Wt,
    const float* __restrict__ b1, const float* __restrict__ b2,
    const float* __restrict__ gamma, const float* __restrict__ beta,
    const float* __restrict__ mean, const float* __restrict__ var,
    float* __restrict__ scale, float* __restrict__ shift) {
    int bid = blockIdx.x, t = threadIdx.x;
    if (bid < CB) {
        // ---- cast fp32 -> bf16 flat [N][128]; zero gcur ----
        int i = bid * 256 + t;
        if (i < NB) gcur[i] = 0;
        float4 v = x[i];               // CB*256 == n4 exactly
        ushort4 o;
        o.x = f2b(v.x); o.y = f2b(v.y); o.z = f2b(v.z); o.w = f2b(v.w);
        xb[i] = o;
    } else if (bid < CB + SB) {
        // ---- graph starts from sorted batch; seed out with bias ----
        int i = (bid - CB) * 256 + t;
        if (i < N_GRAPHS * OUT_CH) outinit[i] = bc[i & (OUT_CH - 1)];
        if (i >= N_NODES) return;
        int b = batch[i];
        if (i == 0) {
            for (int g = 0; g <= b; ++g) starts[g] = 0;
        } else {
            int pb = batch[i - 1];
            for (int g = pb + 1; g <= b; ++g) starts[g] = i;
        }
        if (i == N_NODES - 1) {
            for (int g = b + 1; g <= N_GRAPHS; ++g) starts[g] = N_NODES;
        }
    } else {
        // ---- weight fragments [ct][ks][lane][j] + scale/shift ----
        int i = (bid - CB - SB) * 256 + t;
        if (i < 6 * CH * CH) {
            int mat = i >> 14, r = i & 16383;
            int j = r & 7, bb = r >> 3;
            int lane = bb & 63, cs = bb >> 6;
            int ct = cs >> 2, ks = cs & 3;
            int n = ct * 16 + (lane & 15);
            int k = ks * 32 + (lane >> 4) * 8 + j;
            const float* Wsrc = (mat < 3) ? (W1 + (size_t)mat * CH * CH)
                                          : (W2 + (size_t)(mat - 3) * CH * CH);
            Wt[i] = f2b(Wsrc[k * CH + n]);
        } else {
            int e = i - 6 * CH * CH;
            if (e >= 6 * CH) return;
            int mat = e / CH, c = e % CH;
            if (mat < 3) {
                scale[e] = 1.f;
                shift[e] = b1[mat * CH + c];
            } else {
                int l = mat - 3;
                float inv = gamma[l * CH + c] * rsqrtf(var[l * CH + c] + BN_EPS);
                scale[e] = inv;
                shift[e] = (b2[l * CH + c] - mean[l * CH + c]) * inv + beta[l * CH + c];
            }
        }
    }
}

// ---------------- edge binning: pack = src | (dst&255)<<16, bucket = dst>>8 ----------------
__global__ __launch_bounds__(256) void bin_kernel(const int* __restrict__ src,
                                                  const int* __restrict__ dst,
                                                  int* __restrict__ gcur,
                                                  unsigned* __restrict__ gbuck) {
    __shared__ int lcnt[256];
    __shared__ int lpref[256];
    __shared__ int lpos[NB];
    __shared__ int lbase[NB];
    __shared__ unsigned stage[EPB];
    __shared__ unsigned char sbk[EPB];
    int t = threadIdx.x;
    int e0 = blockIdx.x * EPB;
    int nloc = N_EDGES - e0; if (nloc > EPB) nloc = EPB;

    lcnt[t] = 0;
    __syncthreads();

    int2 ed[16];
    #pragma unroll
    for (int j = 0; j < 16; ++j) {
        int i = j * 256 + t;
        if (i < nloc) {
            ed[j].x = src[e0 + i];
            ed[j].y = dst[e0 + i];
            atomicAdd(&lcnt[ed[j].y >> 8], 1);
        } else ed[j].y = -1;
    }
    __syncthreads();
    int v = lcnt[t];
    lpref[t] = v;
    __syncthreads();
    for (int off = 1; off < 256; off <<= 1) {
        int y = (t >= off) ? lpref[t - off] : 0;
        __syncthreads();
        lpref[t] += y;
        __syncthreads();
    }
    int excl = lpref[t] - v;
    __syncthreads();
    lpref[t] = excl;
    if (t < NB) {
        lpos[t] = excl;
        lbase[t] = atomicAdd(&gcur[t], v);
    }
    __syncthreads();
    #pragma unroll
    for (int j = 0; j < 16; ++j) {
        if (ed[j].y >= 0) {
            int b = ed[j].y >> 8;
            int slot = atomicAdd(&lpos[b], 1);
            stage[slot] = (unsigned)ed[j].x | ((unsigned)(ed[j].y & 255) << 16);
            sbk[slot] = (unsigned char)b;
        }
    }
    __syncthreads();
    for (int i = t; i < nloc; i += 256) {
        int b = sbk[i];
        gbuck[(size_t)b * BCAP + lbase[b] + (i - lpref[b])] = stage[i];
    }
}

// ---------------- per-bucket sort to CSR slots; inline bucket scan; writes rowptr ----------
__global__ __launch_bounds__(256) void place_kernel(const int* __restrict__ gcur,
                                                    const unsigned* __restrict__ gbuck,
                                                    int* __restrict__ rowptr,
                                                    ushort_t* __restrict__ esrc) {
    __shared__ ushort_t ssrc[BCAP];
    __shared__ unsigned char sd[BCAP];
    __shared__ int outS[BCAP];
    __shared__ int cnt[256], pref[256], cur[256];
    __shared__ int sscan[256];
    int b = blockIdx.x, t = threadIdx.x;
    // inline exclusive scan over all bucket sizes -> this bucket's base
    int gv = (t < NB) ? gcur[t] : 0;
    sscan[t] = gv;
    cnt[t] = 0;
    __syncthreads();
    for (int off = 1; off < 256; off <<= 1) {
        int y = (t >= off) ? sscan[t - off] : 0;
        __syncthreads();
        sscan[t] += y;
        __syncthreads();
    }
    int nb = gcur[b];
    int base = sscan[b] - nb;   // exclusive prefix
    for (int i = t; i < nb; i += 256) {
        unsigned p = gbuck[(size_t)b * BCAP + i];
        ssrc[i] = (ushort_t)(p & 0xffffu);
        int dl = (p >> 16) & 0xff;
        sd[i] = (unsigned char)dl;
        atomicAdd(&cnt[dl], 1);
    }
    __syncthreads();
    int v = cnt[t];
    pref[t] = v;
    __syncthreads();
    for (int off = 1; off < 256; off <<= 1) {
        int y = (t >= off) ? pref[t - off] : 0;
        __syncthreads();
        pref[t] += y;
        __syncthreads();
    }
    int excl = pref[t] - v;
    __syncthreads();
    pref[t] = excl;
    cur[t] = 0;
    int idx = (b << 8) + t;
    if (idx < N_NODES) rowptr[idx] = base + excl;
    if (b == NB - 1 && t == 0) rowptr[N_NODES] = N_EDGES;
    __syncthreads();
    for (int i = t; i < nb; i += 256) {
        int dl = sd[i];
        int p = pref[dl] + atomicAdd(&cur[dl], 1);
        outS[p] = ssrc[i];
    }
    __syncthreads();
    for (int i = t; i < nb; i += 256)
        esrc[base + i] = (ushort_t)outS[i];
}

// ---------------- aggregation: pull, wave/node, 16 edges (4KB) in flight ------------------
// dwordx2 per lane, 32 lanes per edge-row: half the VMEM instructions of the dword form,
// identical 256B/edge coalescing. NT store for z (streamed; don't evict gather lines).
__global__ __launch_bounds__(256) void agg_kernel(const unsigned* __restrict__ h2,
                                                  const int* __restrict__ rowptr,
                                                  const ushort_t* __restrict__ esrc,
                                                  unsigned* __restrict__ z2) {
    int wid = (blockIdx.x * 256 + threadIdx.x) >> 6;
    int lane = threadIdx.x & 63;
    int e2 = lane >> 5;       // which edge of a pair
    int l32 = lane & 31;      // dword-pair within the 256B row
    if (wid >= N_NODES) return;
    const unsigned* hp = h2 + 2 * l32;
    float ax = 0.f, ay = 0.f, az = 0.f, aw = 0.f;
    int e = rowptr[wid], end = rowptr[wid + 1];
    for (; e + 16 <= end; e += 16) {
        u32x2 u[8];
        #pragma unroll
        for (int j = 0; j < 8; ++j) {
            int s = esrc[e + 2 * j + e2];
            u[j] = *(const u32x2*)(hp + (size_t)s * 64);
        }
        #pragma unroll
        for (int j = 0; j < 8; ++j) {
            ax += blo(u[j][0]); ay += bhi(u[j][0]);
            az += blo(u[j][1]); aw += bhi(u[j][1]);
        }
    }
    for (; e + 8 <= end; e += 8) {
        u32x2 u[4];
        #pragma unroll
        for (int j = 0; j < 4; ++j) {
            int s = esrc[e + 2 * j + e2];
            u[j] = *(const u32x2*)(hp + (size_t)s * 64);
        }
        #pragma unroll
        for (int j = 0; j < 4; ++j) {
            ax += blo(u[j][0]); ay += bhi(u[j][0]);
            az += blo(u[j][1]); aw += bhi(u[j][1]);
        }
    }
    for (; e + 2 <= end; e += 2) {
        int s = esrc[e + e2];
        u32x2 u = *(const u32x2*)(hp + (size_t)s * 64);
        ax += blo(u[0]); ay += bhi(u[0]);
        az += blo(u[1]); aw += bhi(u[1]);
    }
    if (e + e2 < end) {
        int s = esrc[e + e2];
        u32x2 u = *(const u32x2*)(hp + (size_t)s * 64);
        ax += blo(u[0]); ay += bhi(u[0]);
        az += blo(u[1]); aw += bhi(u[1]);
    }
    // combine the two edge-halves
    ax += __shfl_xor(ax, 32); ay += __shfl_xor(ay, 32);
    az += __shfl_xor(az, 32); aw += __shfl_xor(aw, 32);
    if (e2 == 0) {
        u32x2 self = *(const u32x2*)(hp + (size_t)wid * 64);
        ax += blo(self[0]); ay += bhi(self[0]);
        az += blo(self[1]); aw += bhi(self[1]);
        u32x2 o;
        o[0] = ((unsigned)f2b(ay) << 16) | (unsigned)f2b(ax);
        o[1] = ((unsigned)f2b(aw) << 16) | (unsigned)f2b(az);
        __builtin_nontemporal_store(o, (u32x2*)(z2 + (size_t)wid * 64 + 2 * l32));
    }
}

// ---------------- fused MLP (R8 conflict-free form) ----------------
__global__ __launch_bounds__(512) void mlp_kernel(const ushort_t* __restrict__ A,
                                                  const ushort_t* __restrict__ Wf1,
                                                  const ushort_t* __restrict__ Wf2,
                                                  const float* __restrict__ shift1,
                                                  const float* __restrict__ scale2,
                                                  const float* __restrict__ shift2,
                                                  ushort_t* __restrict__ Out) {
    __shared__ ushort_t sW1[CH * CH];
    __shared__ ushort_t sW2[CH * CH];
    __shared__ ushort_t sS[8][CH * SSTRIDE];

    int t = threadIdx.x;
    int wave = t >> 6, lane = t & 63;
    int quad = lane >> 4, l16 = lane & 15;

    {
        const uint4* g1 = (const uint4*)Wf1;
        const uint4* g2 = (const uint4*)Wf2;
        uint4* s1 = (uint4*)sW1;
        uint4* s2 = (uint4*)sW2;
        for (int i = t; i < 2048; i += 512) { s1[i] = g1[i]; s2[i] = g2[i]; }
    }
    __syncthreads();

    const bf16x8* w1f = (const bf16x8*)sW1;
    const bf16x8* w2f = (const bf16x8*)sW2;
    int wg = blockIdx.x * 8 + wave;

    for (int it = 0; it < 2; ++it) {
        int tile = wg + 2048 * it;
        if (tile >= NTILES) break;
        int arow = tile * 16 + l16;

        bf16x8 af[4];
        #pragma unroll
        for (int ks = 0; ks < 4; ++ks)
            af[ks] = *(const bf16x8*)(A + (size_t)arow * CH + ks * 32 + quad * 8);

        f32x4 acc[8];
        #pragma unroll
        for (int ct = 0; ct < 8; ++ct) acc[ct] = (f32x4){0.f, 0.f, 0.f, 0.f};
        #pragma unroll
        for (int ct = 0; ct < 8; ++ct)
            #pragma unroll
            for (int ks = 0; ks < 4; ++ks)
                acc[ct] = __builtin_amdgcn_mfma_f32_16x16x32_bf16(
                    af[ks], w1f[(ct * 4 + ks) * 64 + lane], acc[ct], 0, 0, 0);

        #pragma unroll
        for (int ct = 0; ct < 8; ++ct) {
            int k = ct * 16 + l16;
            float sh = shift1[k];
            uint2 p;
            p.x = ((unsigned)f2b(fmaxf(acc[ct][1] + sh, 0.f)) << 16)
                |  (unsigned)f2b(fmaxf(acc[ct][0] + sh, 0.f));
            p.y = ((unsigned)f2b(fmaxf(acc[ct][3] + sh, 0.f)) << 16)
                |  (unsigned)f2b(fmaxf(acc[ct][2] + sh, 0.f));
            *(uint2*)&sS[wave][k * SSTRIDE + quad * 4] = p;
        }

        bf16x8 af2[4];
        #pragma unroll
        for (int ks = 0; ks < 4; ++ks)
            #pragma unroll
            for (int j = 0; j < 8; ++j)
                af2[ks][j] = (short)sS[wave][(ks * 32 + quad * 8 + j) * SSTRIDE + l16];

        f32x4 acc2[8];
        #pragma unroll
        for (int ct = 0; ct < 8; ++ct) acc2[ct] = (f32x4){0.f, 0.f, 0.f, 0.f};
        #pragma unroll
        for (int ct = 0; ct < 8; ++ct)
            #pragma unroll
            for (int ks = 0; ks < 4; ++ks)
                acc2[ct] = __builtin_amdgcn_mfma_f32_16x16x32_bf16(
                    af2[ks], w2f[(ct * 4 + ks) * 64 + lane], acc2[ct], 0, 0, 0);

        int row0 = tile * 16;
        #pragma unroll
        for (int ct = 0; ct < 8; ++ct) {
            int col = ct * 16 + l16;
            float sc = scale2[col], sh = shift2[col];
            #pragma unroll
            for (int r = 0; r < 4; ++r) {
                int row = row0 + quad * 4 + r;
                Out[(size_t)row * CH + col] = f2b(fmaxf(acc2[ct][r] * sc + sh, 0.f));
            }
        }
    }
}

// ---------------- pooling fused with classifier: partial matvec + atomic out ----------
__global__ __launch_bounds__(64) void pool_kernel(const unsigned* __restrict__ h2,
                                                  const int* __restrict__ starts,
                                                  const float* __restrict__ Wc,
                                                  float* __restrict__ out) {
    int g = blockIdx.x / NSPLIT, s = blockIdx.x % NSPLIT;
    int c = threadIdx.x;
    int beg = starts[g], end = starts[g + 1];
    float s0 = 0.f, s1 = 0.f;
    for (int n = beg + s; n < end; n += NSPLIT) {
        unsigned u = h2[(size_t)n * 64 + c];
        s0 += blo(u); s1 += bhi(u);
    }
    // partial pooled (channels 2c, 2c+1) x Wc -> 16 outputs, wave-reduce, atomic
    float p[OUT_CH];
    #pragma unroll
    for (int o = 0; o < OUT_CH; ++o)
        p[o] = s0 * Wc[(2 * c) * OUT_CH + o] + s1 * Wc[(2 * c + 1) * OUT_CH + o];
    #pragma unroll
    for (int o = 0; o < OUT_CH; ++o) {
        p[o] += __shfl_xor(p[o], 1);
        p[o] += __shfl_xor(p[o], 2);
        p[o] += __shfl_xor(p[o], 4);
        p[o] += __shfl_xor(p[o], 8);
        p[o] += __shfl_xor(p[o], 16);
        p[o] += __shfl_xor(p[o], 32);
    }
    if (c == 0) {
        #pragma unroll
        for (int o = 0; o < OUT_CH; ++o)
            atomicAdd(&out[g * OUT_CH + o], p[o]);
    }
}

// ---------------- launch ----------------
extern "C" void kernel_launch(void* const* d_in, const int* in_sizes, int n_in,
                              void* d_out, int out_size, void* d_ws, size_t ws_size,
                              hipStream_t stream) {
    const float* x     = (const float*)d_in[0];
    const int*   eidx  = (const int*)d_in[1];
    const int*   batch = (const int*)d_in[2];
    const float* W1    = (const float*)d_in[3];
    const float* b1    = (const float*)d_in[4];
    const float* W2    = (const float*)d_in[5];
    const float* b2    = (const float*)d_in[6];
    const float* gamma = (const float*)d_in[7];
    const float* beta  = (const float*)d_in[8];
    const float* mean  = (const float*)d_in[9];
    const float* var   = (const float*)d_in[10];
    const float* Wc    = (const float*)d_in[11];
    const float* bc    = (const float*)d_in[12];
    float* out = (float*)d_out;

    const int* src = eidx;
    const int* dst = eidx + N_EDGES;

    char* w = (char*)d_ws;
    size_t off = 0;
    auto alloc = [&](size_t bytes) { void* p = w + off; off += (bytes + 255) & ~(size_t)255; return p; };
    int*      gcur   = (int*)alloc(NB * 4);
    unsigned* gbuck  = (unsigned*)alloc((size_t)NB * BCAP * 4);
    int*      rowptr = (int*)alloc((N_NODES + 1) * 4);
    ushort_t* esrc   = (ushort_t*)alloc(N_EDGES * 2);
    int*      starts = (int*)alloc((N_GRAPHS + 1) * 4);
    ushort_t* Bh     = (ushort_t*)alloc((size_t)N_NODES * CH * 2);
    ushort_t* Bz     = (ushort_t*)alloc((size_t)N_NODES * CH * 2);
    ushort_t* Wt     = (ushort_t*)alloc((size_t)6 * CH * CH * 2);
    float*    scale  = (float*)alloc(6 * CH * 4);
    float*    shift  = (float*)alloc(6 * CH * 4);
    (void)ws_size; (void)n_in; (void)in_sizes; (void)out_size;

    setup_kernel<<<CB + SB + PB, 256, 0, stream>>>(
        (const float4*)x, (ushort4*)Bh, gcur,
        batch, starts, out, bc,
        W1, W2, Wt, b1, b2, gamma, beta, mean, var, scale, shift);
    bin_kernel<<<(N_EDGES + EPB - 1) / EPB, 256, 0, stream>>>(src, dst, gcur, gbuck);
    place_kernel<<<NB, 256, 0, stream>>>(gcur, gbuck, rowptr, esrc);

    const int agg_grid = (N_NODES + 3) / 4;

    for (int i = 0; i < N_LAYERS; ++i) {
        agg_kernel<<<agg_grid, 256, 0, stream>>>((const unsigned*)Bh, rowptr, esrc,
                                                 (unsigned*)Bz);
        mlp_kernel<<<256, 512, 0, stream>>>(Bz,
                                            Wt + (size_t)i * CH * CH,
                                            Wt + (size_t)(3 + i) * CH * CH,
                                            shift + i * CH,
                                            scale + (3 + i) * CH,
                                            shift + (3 + i) * CH,
                                            Bh);
    }

    pool_kernel<<<N_GRAPHS * NSPLIT, 64, 0, stream>>>((const unsigned*)Bh, starts, Wc, out);
}

// Round 3
// 287.659 us; speedup vs baseline: 1.3827x; 1.0132x over previous
//
#include <hip/hip_runtime.h>

#define N_NODES 50000
#define N_EDGES 800000
#define CH 128
#define N_GRAPHS 128
#define N_LAYERS 3
#define OUT_CH 16
#define BN_EPS 1e-5f
#define NSPLIT 32
#define NB 196            // dst>>8 buckets (256 dsts each)
#define BCAP 4608
#define EPB 4096
#define NTILES (N_NODES / 16)      // 3125 exact
// setup_kernel block partition
#define CB 6250            // cast blocks (1.6M float4 / 256)
#define SB 196             // starts blocks
#define PB 388             // prep blocks

typedef unsigned short ushort_t;
typedef __attribute__((ext_vector_type(8))) short bf16x8;
typedef __attribute__((ext_vector_type(4))) float f32x4;

__device__ inline ushort_t f2b(float f) {
    unsigned u = __float_as_uint(f);
    unsigned r = (u + 0x7fffu + ((u >> 16) & 1u)) >> 16;
    return (ushort_t)r;
}
__device__ inline float blo(unsigned u) { return __uint_as_float(u << 16); }
__device__ inline float bhi(unsigned u) { return __uint_as_float(u & 0xffff0000u); }

// ---------------- merged setup: cast | starts+out-init | weight/epilogue prep ----------
__global__ __launch_bounds__(256) void setup_kernel(
    const float4* __restrict__ x, ushort4* __restrict__ xb, int* __restrict__ gcur,
    const int* __restrict__ batch, int* __restrict__ starts, float* __restrict__ outinit,
    const float* __restrict__ bc,
    const float* __restrict__ W1, const float* __restrict__ W2, ushort_t* __restrict__ Wt,
    const float* __restrict__ b1, const float* __restrict__ b2,
    const float* __restrict__ gamma, const float* __restrict__ beta,
    const float* __restrict__ mean, const float* __restrict__ var,
    float* __restrict__ scale, float* __restrict__ shift) {
    int bid = blockIdx.x, t = threadIdx.x;
    if (bid < CB) {
        // ---- cast fp32 -> bf16 flat [N][128]; zero gcur ----
        int i = bid * 256 + t;
        if (i < NB) gcur[i] = 0;
        float4 v = x[i];               // CB*256 == n4 exactly
        ushort4 o;
        o.x = f2b(v.x); o.y = f2b(v.y); o.z = f2b(v.z); o.w = f2b(v.w);
        xb[i] = o;
    } else if (bid < CB + SB) {
        // ---- graph starts from sorted batch; seed out with bias ----
        int i = (bid - CB) * 256 + t;
        if (i < N_GRAPHS * OUT_CH) outinit[i] = bc[i & (OUT_CH - 1)];
        if (i >= N_NODES) return;
        int b = batch[i];
        if (i == 0) {
            for (int g = 0; g <= b; ++g) starts[g] = 0;
        } else {
            int pb = batch[i - 1];
            for (int g = pb + 1; g <= b; ++g) starts[g] = i;
        }
        if (i == N_NODES - 1) {
            for (int g = b + 1; g <= N_GRAPHS; ++g) starts[g] = N_NODES;
        }
    } else {
        // ---- weight fragments [ct][ks][lane][j] + scale/shift ----
        int i = (bid - CB - SB) * 256 + t;
        if (i < 6 * CH * CH) {
            int mat = i >> 14, r = i & 16383;
            int j = r & 7, bb = r >> 3;
            int lane = bb & 63, cs = bb >> 6;
            int ct = cs >> 2, ks = cs & 3;
            int n = ct * 16 + (lane & 15);
            int k = ks * 32 + (lane >> 4) * 8 + j;
            const float* Wsrc = (mat < 3) ? (W1 + (size_t)mat * CH * CH)
                                          : (W2 + (size_t)(mat - 3) * CH * CH);
            Wt[i] = f2b(Wsrc[k * CH + n]);
        } else {
            int e = i - 6 * CH * CH;
            if (e >= 6 * CH) return;
            int mat = e / CH, c = e % CH;
            if (mat < 3) {
                scale[e] = 1.f;
                shift[e] = b1[mat * CH + c];
            } else {
                int l = mat - 3;
                float inv = gamma[l * CH + c] * rsqrtf(var[l * CH + c] + BN_EPS);
                scale[e] = inv;
                shift[e] = (b2[l * CH + c] - mean[l * CH + c]) * inv + beta[l * CH + c];
            }
        }
    }
}

// ---------------- edge binning: pack = src | (dst&255)<<16, bucket = dst>>8 ----------------
__global__ __launch_bounds__(256) void bin_kernel(const int* __restrict__ src,
                                                  const int* __restrict__ dst,
                                                  int* __restrict__ gcur,
                                                  unsigned* __restrict__ gbuck) {
    __shared__ int lcnt[256];
    __shared__ int lpref[256];
    __shared__ int lpos[NB];
    __shared__ int lbase[NB];
    __shared__ unsigned stage[EPB];
    __shared__ unsigned char sbk[EPB];
    int t = threadIdx.x;
    int e0 = blockIdx.x * EPB;
    int nloc = N_EDGES - e0; if (nloc > EPB) nloc = EPB;

    lcnt[t] = 0;
    __syncthreads();

    int2 ed[16];
    #pragma unroll
    for (int j = 0; j < 16; ++j) {
        int i = j * 256 + t;
        if (i < nloc) {
            ed[j].x = src[e0 + i];
            ed[j].y = dst[e0 + i];
            atomicAdd(&lcnt[ed[j].y >> 8], 1);
        } else ed[j].y = -1;
    }
    __syncthreads();
    int v = lcnt[t];
    lpref[t] = v;
    __syncthreads();
    for (int off = 1; off < 256; off <<= 1) {
        int y = (t >= off) ? lpref[t - off] : 0;
        __syncthreads();
        lpref[t] += y;
        __syncthreads();
    }
    int excl = lpref[t] - v;
    __syncthreads();
    lpref[t] = excl;
    if (t < NB) {
        lpos[t] = excl;
        lbase[t] = atomicAdd(&gcur[t], v);
    }
    __syncthreads();
    #pragma unroll
    for (int j = 0; j < 16; ++j) {
        if (ed[j].y >= 0) {
            int b = ed[j].y >> 8;
            int slot = atomicAdd(&lpos[b], 1);
            stage[slot] = (unsigned)ed[j].x | ((unsigned)(ed[j].y & 255) << 16);
            sbk[slot] = (unsigned char)b;
        }
    }
    __syncthreads();
    for (int i = t; i < nloc; i += 256) {
        int b = sbk[i];
        gbuck[(size_t)b * BCAP + lbase[b] + (i - lpref[b])] = stage[i];
    }
}

// ---------------- per-bucket sort to CSR slots; inline bucket scan; writes rowptr ----------
__global__ __launch_bounds__(256) void place_kernel(const int* __restrict__ gcur,
                                                    const unsigned* __restrict__ gbuck,
                                                    int* __restrict__ rowptr,
                                                    ushort_t* __restrict__ esrc) {
    __shared__ ushort_t ssrc[BCAP];
    __shared__ unsigned char sd[BCAP];
    __shared__ int outS[BCAP];
    __shared__ int cnt[256], pref[256], cur[256];
    __shared__ int sscan[256];
    int b = blockIdx.x, t = threadIdx.x;
    // inline exclusive scan over all bucket sizes -> this bucket's base
    int gv = (t < NB) ? gcur[t] : 0;
    sscan[t] = gv;
    cnt[t] = 0;
    __syncthreads();
    for (int off = 1; off < 256; off <<= 1) {
        int y = (t >= off) ? sscan[t - off] : 0;
        __syncthreads();
        sscan[t] += y;
        __syncthreads();
    }
    int nb = gcur[b];
    int base = sscan[b] - nb;   // exclusive prefix
    for (int i = t; i < nb; i += 256) {
        unsigned p = gbuck[(size_t)b * BCAP + i];
        ssrc[i] = (ushort_t)(p & 0xffffu);
        int dl = (p >> 16) & 0xff;
        sd[i] = (unsigned char)dl;
        atomicAdd(&cnt[dl], 1);
    }
    __syncthreads();
    int v = cnt[t];
    pref[t] = v;
    __syncthreads();
    for (int off = 1; off < 256; off <<= 1) {
        int y = (t >= off) ? pref[t - off] : 0;
        __syncthreads();
        pref[t] += y;
        __syncthreads();
    }
    int excl = pref[t] - v;
    __syncthreads();
    pref[t] = excl;
    cur[t] = 0;
    int idx = (b << 8) + t;
    if (idx < N_NODES) rowptr[idx] = base + excl;
    if (b == NB - 1 && t == 0) rowptr[N_NODES] = N_EDGES;
    __syncthreads();
    for (int i = t; i < nb; i += 256) {
        int dl = sd[i];
        int p = pref[dl] + atomicAdd(&cur[dl], 1);
        outS[p] = ssrc[i];
    }
    __syncthreads();
    for (int i = t; i < nb; i += 256)
        esrc[base + i] = (ushort_t)outS[i];
}

// ---------------- aggregation: pull, wave/node, 16-deep gather unroll, u16 indices --------
// (round-0 proven form: 16 outstanding dword gathers per lane = max MLP for the
//  latency-bound random L3/L2 accesses; plain stores so mlp reads z from cache)
__global__ __launch_bounds__(256) void agg_kernel(const unsigned* __restrict__ h2,
                                                  const int* __restrict__ rowptr,
                                                  const ushort_t* __restrict__ esrc,
                                                  unsigned* __restrict__ z2) {
    int wid = (blockIdx.x * 256 + threadIdx.x) >> 6;
    int lane = threadIdx.x & 63;
    if (wid >= N_NODES) return;
    unsigned self = h2[(size_t)wid * 64 + lane];
    float ax = blo(self), ay = bhi(self);
    int e = rowptr[wid], end = rowptr[wid + 1];
    for (; e + 16 <= end; e += 16) {
        unsigned u[16];
        #pragma unroll
        for (int j = 0; j < 16; ++j) {
            int s = esrc[e + j];
            u[j] = h2[(size_t)s * 64 + lane];
        }
        #pragma unroll
        for (int j = 0; j < 16; ++j) { ax += blo(u[j]); ay += bhi(u[j]); }
    }
    for (; e + 8 <= end; e += 8) {
        unsigned u[8];
        #pragma unroll
        for (int j = 0; j < 8; ++j) {
            int s = esrc[e + j];
            u[j] = h2[(size_t)s * 64 + lane];
        }
        #pragma unroll
        for (int j = 0; j < 8; ++j) { ax += blo(u[j]); ay += bhi(u[j]); }
    }
    for (; e + 4 <= end; e += 4) {
        unsigned u[4];
        #pragma unroll
        for (int j = 0; j < 4; ++j) {
            int s = esrc[e + j];
            u[j] = h2[(size_t)s * 64 + lane];
        }
        #pragma unroll
        for (int j = 0; j < 4; ++j) { ax += blo(u[j]); ay += bhi(u[j]); }
    }
    for (; e < end; ++e) {
        unsigned u = h2[(size_t)esrc[e] * 64 + lane];
        ax += blo(u); ay += bhi(u);
    }
    z2[(size_t)wid * 64 + lane] = ((unsigned)f2b(ay) << 16) | (unsigned)f2b(ax);
}

// ---------------- single-GEMM pass: Out = relu((A @ W) * scale + shift) -------------------
// 32KB weight LDS, 4 waves/block, 1 tile/wave, grid 782 -> ~3 blocks/CU, 12 waves/CU.
// Used twice per layer: (z,W1,1,b1)->Mid and (Mid,W2,bnscale,bnshift)->h.
__global__ __launch_bounds__(256) void gemm_kernel(const ushort_t* __restrict__ A,
                                                   const ushort_t* __restrict__ Wf,
                                                   const float* __restrict__ scale,
                                                   const float* __restrict__ shift,
                                                   ushort_t* __restrict__ Out) {
    __shared__ ushort_t sW[CH * CH];
    int t = threadIdx.x;
    int wave = t >> 6, lane = t & 63;
    int quad = lane >> 4, l16 = lane & 15;
    {
        const uint4* g = (const uint4*)Wf;
        uint4* s = (uint4*)sW;
        #pragma unroll
        for (int i = 0; i < 8; ++i) s[i * 256 + t] = g[i * 256 + t];
    }
    __syncthreads();
    const bf16x8* wf = (const bf16x8*)sW;

    int tile = blockIdx.x * 4 + wave;
    if (tile >= NTILES) return;
    int arow = tile * 16 + l16;

    bf16x8 af[4];
    #pragma unroll
    for (int ks = 0; ks < 4; ++ks)
        af[ks] = *(const bf16x8*)(A + (size_t)arow * CH + ks * 32 + quad * 8);

    f32x4 acc[8];
    #pragma unroll
    for (int ct = 0; ct < 8; ++ct) acc[ct] = (f32x4){0.f, 0.f, 0.f, 0.f};
    #pragma unroll
    for (int ct = 0; ct < 8; ++ct)
        #pragma unroll
        for (int ks = 0; ks < 4; ++ks)
            acc[ct] = __builtin_amdgcn_mfma_f32_16x16x32_bf16(
                af[ks], wf[(ct * 4 + ks) * 64 + lane], acc[ct], 0, 0, 0);

    int row0 = tile * 16 + quad * 4;
    #pragma unroll
    for (int ct = 0; ct < 8; ++ct) {
        int col = ct * 16 + l16;
        float sc = scale[col], sh = shift[col];
        #pragma unroll
        for (int r = 0; r < 4; ++r)
            Out[(size_t)(row0 + r) * CH + col] = f2b(fmaxf(acc[ct][r] * sc + sh, 0.f));
    }
}

// ---------------- pooling fused with classifier: partial matvec + atomic out ----------
__global__ __launch_bounds__(64) void pool_kernel(const unsigned* __restrict__ h2,
                                                  const int* __restrict__ starts,
                                                  const float* __restrict__ Wc,
                                                  float* __restrict__ out) {
    int g = blockIdx.x / NSPLIT, s = blockIdx.x % NSPLIT;
    int c = threadIdx.x;
    int beg = starts[g], end = starts[g + 1];
    float s0 = 0.f, s1 = 0.f;
    for (int n = beg + s; n < end; n += NSPLIT) {
        unsigned u = h2[(size_t)n * 64 + c];
        s0 += blo(u); s1 += bhi(u);
    }
    // partial pooled (channels 2c, 2c+1) x Wc -> 16 outputs, wave-reduce, atomic
    float p[OUT_CH];
    #pragma unroll
    for (int o = 0; o < OUT_CH; ++o)
        p[o] = s0 * Wc[(2 * c) * OUT_CH + o] + s1 * Wc[(2 * c + 1) * OUT_CH + o];
    #pragma unroll
    for (int o = 0; o < OUT_CH; ++o) {
        p[o] += __shfl_xor(p[o], 1);
        p[o] += __shfl_xor(p[o], 2);
        p[o] += __shfl_xor(p[o], 4);
        p[o] += __shfl_xor(p[o], 8);
        p[o] += __shfl_xor(p[o], 16);
        p[o] += __shfl_xor(p[o], 32);
    }
    if (c == 0) {
        #pragma unroll
        for (int o = 0; o < OUT_CH; ++o)
            atomicAdd(&out[g * OUT_CH + o], p[o]);
    }
}

// ---------------- launch ----------------
extern "C" void kernel_launch(void* const* d_in, const int* in_sizes, int n_in,
                              void* d_out, int out_size, void* d_ws, size_t ws_size,
                              hipStream_t stream) {
    const float* x     = (const float*)d_in[0];
    const int*   eidx  = (const int*)d_in[1];
    const int*   batch = (const int*)d_in[2];
    const float* W1    = (const float*)d_in[3];
    const float* b1    = (const float*)d_in[4];
    const float* W2    = (const float*)d_in[5];
    const float* b2    = (const float*)d_in[6];
    const float* gamma = (const float*)d_in[7];
    const float* beta  = (const float*)d_in[8];
    const float* mean  = (const float*)d_in[9];
    const float* var   = (const float*)d_in[10];
    const float* Wc    = (const float*)d_in[11];
    const float* bc    = (const float*)d_in[12];
    float* out = (float*)d_out;

    const int* src = eidx;
    const int* dst = eidx + N_EDGES;

    char* w = (char*)d_ws;
    size_t off = 0;
    auto alloc = [&](size_t bytes) { void* p = w + off; off += (bytes + 255) & ~(size_t)255; return p; };
    int*      gcur   = (int*)alloc(NB * 4);
    unsigned* gbuck  = (unsigned*)alloc((size_t)NB * BCAP * 4);
    int*      rowptr = (int*)alloc((N_NODES + 1) * 4);
    ushort_t* esrc   = (ushort_t*)alloc(N_EDGES * 2);
    int*      starts = (int*)alloc((N_GRAPHS + 1) * 4);
    ushort_t* Bh     = (ushort_t*)alloc((size_t)N_NODES * CH * 2);
    ushort_t* Bz     = (ushort_t*)alloc((size_t)N_NODES * CH * 2);
    ushort_t* Bm     = (ushort_t*)alloc((size_t)N_NODES * CH * 2);
    ushort_t* Wt     = (ushort_t*)alloc((size_t)6 * CH * CH * 2);
    float*    scale  = (float*)alloc(6 * CH * 4);
    float*    shift  = (float*)alloc(6 * CH * 4);
    (void)ws_size; (void)n_in; (void)in_sizes; (void)out_size;

    setup_kernel<<<CB + SB + PB, 256, 0, stream>>>(
        (const float4*)x, (ushort4*)Bh, gcur,
        batch, starts, out, bc,
        W1, W2, Wt, b1, b2, gamma, beta, mean, var, scale, shift);
    bin_kernel<<<(N_EDGES + EPB - 1) / EPB, 256, 0, stream>>>(src, dst, gcur, gbuck);
    place_kernel<<<NB, 256, 0, stream>>>(gcur, gbuck, rowptr, esrc);

    const int agg_grid = (N_NODES + 3) / 4;
    const int gemm_grid = (NTILES + 3) / 4;

    for (int i = 0; i < N_LAYERS; ++i) {
        agg_kernel<<<agg_grid, 256, 0, stream>>>((const unsigned*)Bh, rowptr, esrc,
                                                 (unsigned*)Bz);
        gemm_kernel<<<gemm_grid, 256, 0, stream>>>(Bz,
                                                   Wt + (size_t)i * CH * CH,
                                                   scale + i * CH,
                                                   shift + i * CH,
                                                   Bm);
        gemm_kernel<<<gemm_grid, 256, 0, stream>>>(Bm,
                                                   Wt + (size_t)(3 + i) * CH * CH,
                                                   scale + (3 + i) * CH,
                                                   shift + (3 + i) * CH,
                                                   Bh);
    }

    pool_kernel<<<N_GRAPHS * NSPLIT, 64, 0, stream>>>((const unsigned*)Bh, starts, Wc, out);
}

// Round 4
// 269.443 us; speedup vs baseline: 1.4762x; 1.0676x over previous
//
#include <hip/hip_runtime.h>

#define N_NODES 50000
#define N_EDGES 800000
#define CH 128
#define N_GRAPHS 128
#define N_LAYERS 3
#define OUT_CH 16
#define BN_EPS 1e-5f
#define NSPLIT 32
#define NB 196            // dst>>8 buckets (256 dsts each)
#define BCAP 4608
#define EPB 4096
#define NTILES (N_NODES / 16)      // 3125 exact
#define SSTRIDE 20
// setup_kernel block partition
#define CB 6250            // cast blocks (1.6M float4 / 256)
#define SB 196             // starts blocks
#define PB 388             // prep blocks

typedef unsigned short ushort_t;
typedef __attribute__((ext_vector_type(8))) short bf16x8;
typedef __attribute__((ext_vector_type(4))) float f32x4;

__device__ inline ushort_t f2b(float f) {
    unsigned u = __float_as_uint(f);
    unsigned r = (u + 0x7fffu + ((u >> 16) & 1u)) >> 16;
    return (ushort_t)r;
}
__device__ inline float blo(unsigned u) { return __uint_as_float(u << 16); }
__device__ inline float bhi(unsigned u) { return __uint_as_float(u & 0xffff0000u); }

// ---------------- merged setup: cast | starts+out-init | weight/epilogue prep ----------
__global__ __launch_bounds__(256) void setup_kernel(
    const float4* __restrict__ x, ushort4* __restrict__ xb, int* __restrict__ gcur,
    const int* __restrict__ batch, int* __restrict__ starts, float* __restrict__ outinit,
    const float* __restrict__ bc,
    const float* __restrict__ W1, const float* __restrict__ W2, ushort_t* __restrict__ Wt,
    const float* __restrict__ b1, const float* __restrict__ b2,
    const float* __restrict__ gamma, const float* __restrict__ beta,
    const float* __restrict__ mean, const float* __restrict__ var,
    float* __restrict__ scale, float* __restrict__ shift) {
    int bid = blockIdx.x, t = threadIdx.x;
    if (bid < CB) {
        // ---- cast fp32 -> bf16 flat [N][128]; zero gcur ----
        int i = bid * 256 + t;
        if (i < NB) gcur[i] = 0;
        float4 v = x[i];               // CB*256 == n4 exactly
        ushort4 o;
        o.x = f2b(v.x); o.y = f2b(v.y); o.z = f2b(v.z); o.w = f2b(v.w);
        xb[i] = o;
    } else if (bid < CB + SB) {
        // ---- graph starts from sorted batch; seed out with bias ----
        int i = (bid - CB) * 256 + t;
        if (i < N_GRAPHS * OUT_CH) outinit[i] = bc[i & (OUT_CH - 1)];
        if (i >= N_NODES) return;
        int b = batch[i];
        if (i == 0) {
            for (int g = 0; g <= b; ++g) starts[g] = 0;
        } else {
            int pb = batch[i - 1];
            for (int g = pb + 1; g <= b; ++g) starts[g] = i;
        }
        if (i == N_NODES - 1) {
            for (int g = b + 1; g <= N_GRAPHS; ++g) starts[g] = N_NODES;
        }
    } else {
        // ---- weight fragments [ct][ks][lane][j] + scale/shift ----
        int i = (bid - CB - SB) * 256 + t;
        if (i < 6 * CH * CH) {
            int mat = i >> 14, r = i & 16383;
            int j = r & 7, bb = r >> 3;
            int lane = bb & 63, cs = bb >> 6;
            int ct = cs >> 2, ks = cs & 3;
            int n = ct * 16 + (lane & 15);
            int k = ks * 32 + (lane >> 4) * 8 + j;
            const float* Wsrc = (mat < 3) ? (W1 + (size_t)mat * CH * CH)
                                          : (W2 + (size_t)(mat - 3) * CH * CH);
            Wt[i] = f2b(Wsrc[k * CH + n]);
        } else {
            int e = i - 6 * CH * CH;
            if (e >= 6 * CH) return;
            int mat = e / CH, c = e % CH;
            if (mat < 3) {
                scale[e] = 1.f;
                shift[e] = b1[mat * CH + c];
            } else {
                int l = mat - 3;
                float inv = gamma[l * CH + c] * rsqrtf(var[l * CH + c] + BN_EPS);
                scale[e] = inv;
                shift[e] = (b2[l * CH + c] - mean[l * CH + c]) * inv + beta[l * CH + c];
            }
        }
    }
}

// ---------------- edge binning: pack = src | (dst&255)<<16, bucket = dst>>8 ----------------
__global__ __launch_bounds__(256) void bin_kernel(const int* __restrict__ src,
                                                  const int* __restrict__ dst,
                                                  int* __restrict__ gcur,
                                                  unsigned* __restrict__ gbuck) {
    __shared__ int lcnt[256];
    __shared__ int lpref[256];
    __shared__ int lpos[NB];
    __shared__ int lbase[NB];
    __shared__ unsigned stage[EPB];
    __shared__ unsigned char sbk[EPB];
    int t = threadIdx.x;
    int e0 = blockIdx.x * EPB;
    int nloc = N_EDGES - e0; if (nloc > EPB) nloc = EPB;

    lcnt[t] = 0;
    __syncthreads();

    int2 ed[16];
    #pragma unroll
    for (int j = 0; j < 16; ++j) {
        int i = j * 256 + t;
        if (i < nloc) {
            ed[j].x = src[e0 + i];
            ed[j].y = dst[e0 + i];
            atomicAdd(&lcnt[ed[j].y >> 8], 1);
        } else ed[j].y = -1;
    }
    __syncthreads();
    int v = lcnt[t];
    lpref[t] = v;
    __syncthreads();
    for (int off = 1; off < 256; off <<= 1) {
        int y = (t >= off) ? lpref[t - off] : 0;
        __syncthreads();
        lpref[t] += y;
        __syncthreads();
    }
    int excl = lpref[t] - v;
    __syncthreads();
    lpref[t] = excl;
    if (t < NB) {
        lpos[t] = excl;
        lbase[t] = atomicAdd(&gcur[t], v);
    }
    __syncthreads();
    #pragma unroll
    for (int j = 0; j < 16; ++j) {
        if (ed[j].y >= 0) {
            int b = ed[j].y >> 8;
            int slot = atomicAdd(&lpos[b], 1);
            stage[slot] = (unsigned)ed[j].x | ((unsigned)(ed[j].y & 255) << 16);
            sbk[slot] = (unsigned char)b;
        }
    }
    __syncthreads();
    for (int i = t; i < nloc; i += 256) {
        int b = sbk[i];
        gbuck[(size_t)b * BCAP + lbase[b] + (i - lpref[b])] = stage[i];
    }
}

// ---------------- per-bucket sort to CSR slots; inline bucket scan; writes rowptr ----------
__global__ __launch_bounds__(256) void place_kernel(const int* __restrict__ gcur,
                                                    const unsigned* __restrict__ gbuck,
                                                    int* __restrict__ rowptr,
                                                    ushort_t* __restrict__ esrc) {
    __shared__ ushort_t ssrc[BCAP];
    __shared__ unsigned char sd[BCAP];
    __shared__ int outS[BCAP];
    __shared__ int cnt[256], pref[256], cur[256];
    __shared__ int sscan[256];
    int b = blockIdx.x, t = threadIdx.x;
    // inline exclusive scan over all bucket sizes -> this bucket's base
    int gv = (t < NB) ? gcur[t] : 0;
    sscan[t] = gv;
    cnt[t] = 0;
    __syncthreads();
    for (int off = 1; off < 256; off <<= 1) {
        int y = (t >= off) ? sscan[t - off] : 0;
        __syncthreads();
        sscan[t] += y;
        __syncthreads();
    }
    int nb = gcur[b];
    int base = sscan[b] - nb;   // exclusive prefix
    for (int i = t; i < nb; i += 256) {
        unsigned p = gbuck[(size_t)b * BCAP + i];
        ssrc[i] = (ushort_t)(p & 0xffffu);
        int dl = (p >> 16) & 0xff;
        sd[i] = (unsigned char)dl;
        atomicAdd(&cnt[dl], 1);
    }
    __syncthreads();
    int v = cnt[t];
    pref[t] = v;
    __syncthreads();
    for (int off = 1; off < 256; off <<= 1) {
        int y = (t >= off) ? pref[t - off] : 0;
        __syncthreads();
        pref[t] += y;
        __syncthreads();
    }
    int excl = pref[t] - v;
    __syncthreads();
    pref[t] = excl;
    cur[t] = 0;
    int idx = (b << 8) + t;
    if (idx < N_NODES) rowptr[idx] = base + excl;
    if (b == NB - 1 && t == 0) rowptr[N_NODES] = N_EDGES;
    __syncthreads();
    for (int i = t; i < nb; i += 256) {
        int dl = sd[i];
        int p = pref[dl] + atomicAdd(&cur[dl], 1);
        outS[p] = ssrc[i];
    }
    __syncthreads();
    for (int i = t; i < nb; i += 256)
        esrc[base + i] = (ushort_t)outS[i];
}

// ---------------- fully fused layer: agg (r0 gather) + MLP1 + BN-folded MLP2 --------------
// 512 thr = 8 waves, one 16-node tile. Phase A: wave aggregates 2 nodes (16-deep pipeline)
// -> z tile in LDS. Phase B: wave w = col-tile w of relu(z@W1+b1), weights from L2,
// mid in transposed LDS (SSTRIDE pad). Phase C: wave w = col-tile w of BN(mid@W2)+ReLU -> h.
// LDS 9.5KB, launch_bounds(512,8) -> 4 blocks/CU = 32 waves/CU (same gather concurrency
// as standalone agg). Removes z/Mid global round-trips and 2 dispatches per layer.
__global__ __launch_bounds__(512, 8) void layer_kernel(
    const unsigned* __restrict__ h2, const int* __restrict__ rowptr,
    const ushort_t* __restrict__ esrc,
    const ushort_t* __restrict__ Wf1, const ushort_t* __restrict__ Wf2,
    const float* __restrict__ shift1, const float* __restrict__ scale2,
    const float* __restrict__ shift2, ushort_t* __restrict__ hout) {
    __shared__ unsigned zt[16][68];            // z tile, u32 = 2 bf16; 68-dword row stride
    __shared__ ushort_t sS[CH * SSTRIDE];      // mid, transposed [k][row(16)+4 pad]

    int t = threadIdx.x;
    int wave = t >> 6, lane = t & 63;
    int quad = lane >> 4, l16 = lane & 15;
    int row0 = blockIdx.x * 16;

    // ---- phase A: aggregate 2 nodes per wave ----
    for (int nn = 0; nn < 2; ++nn) {
        int node = row0 + wave * 2 + nn;
        unsigned self = h2[(size_t)node * 64 + lane];
        float ax = blo(self), ay = bhi(self);
        int e = rowptr[node], end = rowptr[node + 1];
        for (; e + 16 <= end; e += 16) {
            unsigned u[16];
            #pragma unroll
            for (int j = 0; j < 16; ++j) {
                int s = esrc[e + j];
                u[j] = h2[(size_t)s * 64 + lane];
            }
            #pragma unroll
            for (int j = 0; j < 16; ++j) { ax += blo(u[j]); ay += bhi(u[j]); }
        }
        for (; e + 8 <= end; e += 8) {
            unsigned u[8];
            #pragma unroll
            for (int j = 0; j < 8; ++j) {
                int s = esrc[e + j];
                u[j] = h2[(size_t)s * 64 + lane];
            }
            #pragma unroll
            for (int j = 0; j < 8; ++j) { ax += blo(u[j]); ay += bhi(u[j]); }
        }
        for (; e + 4 <= end; e += 4) {
            unsigned u[4];
            #pragma unroll
            for (int j = 0; j < 4; ++j) {
                int s = esrc[e + j];
                u[j] = h2[(size_t)s * 64 + lane];
            }
            #pragma unroll
            for (int j = 0; j < 4; ++j) { ax += blo(u[j]); ay += bhi(u[j]); }
        }
        for (; e < end; ++e) {
            unsigned u = h2[(size_t)esrc[e] * 64 + lane];
            ax += blo(u); ay += bhi(u);
        }
        zt[wave * 2 + nn][lane] = ((unsigned)f2b(ay) << 16) | (unsigned)f2b(ax);
    }
    __syncthreads();

    // ---- phase B: gemm1 col-tile ct = wave; mid -> sS (transposed, r0 packing) ----
    {
        bf16x8 af[4];
        #pragma unroll
        for (int ks = 0; ks < 4; ++ks)
            af[ks] = *(const bf16x8*)((const ushort_t*)&zt[l16][0] + ks * 32 + quad * 8);
        bf16x8 w1[4];
        #pragma unroll
        for (int ks = 0; ks < 4; ++ks)
            w1[ks] = *(const bf16x8*)(Wf1 + ((size_t)(wave * 4 + ks) * 64 + lane) * 8);
        f32x4 acc = (f32x4){0.f, 0.f, 0.f, 0.f};
        #pragma unroll
        for (int ks = 0; ks < 4; ++ks)
            acc = __builtin_amdgcn_mfma_f32_16x16x32_bf16(af[ks], w1[ks], acc, 0, 0, 0);
        int k = wave * 16 + l16;
        float sh = shift1[k];
        uint2 p;
        p.x = ((unsigned)f2b(fmaxf(acc[1] + sh, 0.f)) << 16)
            |  (unsigned)f2b(fmaxf(acc[0] + sh, 0.f));
        p.y = ((unsigned)f2b(fmaxf(acc[3] + sh, 0.f)) << 16)
            |  (unsigned)f2b(fmaxf(acc[2] + sh, 0.f));
        *(uint2*)&sS[k * SSTRIDE + quad * 4] = p;
    }
    __syncthreads();

    // ---- phase C: gemm2 col-tile ct = wave; BN-folded epilogue -> hout ----
    {
        bf16x8 af2[4];
        #pragma unroll
        for (int ks = 0; ks < 4; ++ks)
            #pragma unroll
            for (int j = 0; j < 8; ++j)
                af2[ks][j] = (short)sS[(ks * 32 + quad * 8 + j) * SSTRIDE + l16];
        bf16x8 w2[4];
        #pragma unroll
        for (int ks = 0; ks < 4; ++ks)
            w2[ks] = *(const bf16x8*)(Wf2 + ((size_t)(wave * 4 + ks) * 64 + lane) * 8);
        f32x4 acc = (f32x4){0.f, 0.f, 0.f, 0.f};
        #pragma unroll
        for (int ks = 0; ks < 4; ++ks)
            acc = __builtin_amdgcn_mfma_f32_16x16x32_bf16(af2[ks], w2[ks], acc, 0, 0, 0);
        int col = wave * 16 + l16;
        float sc = scale2[col], sh = shift2[col];
        #pragma unroll
        for (int r = 0; r < 4; ++r) {
            int row = row0 + quad * 4 + r;
            hout[(size_t)row * CH + col] = f2b(fmaxf(acc[r] * sc + sh, 0.f));
        }
    }
}

// ---------------- pooling fused with classifier: partial matvec + atomic out ----------
__global__ __launch_bounds__(64) void pool_kernel(const unsigned* __restrict__ h2,
                                                  const int* __restrict__ starts,
                                                  const float* __restrict__ Wc,
                                                  float* __restrict__ out) {
    int g = blockIdx.x / NSPLIT, s = blockIdx.x % NSPLIT;
    int c = threadIdx.x;
    int beg = starts[g], end = starts[g + 1];
    float s0 = 0.f, s1 = 0.f;
    for (int n = beg + s; n < end; n += NSPLIT) {
        unsigned u = h2[(size_t)n * 64 + c];
        s0 += blo(u); s1 += bhi(u);
    }
    // partial pooled (channels 2c, 2c+1) x Wc -> 16 outputs, wave-reduce, atomic
    float p[OUT_CH];
    #pragma unroll
    for (int o = 0; o < OUT_CH; ++o)
        p[o] = s0 * Wc[(2 * c) * OUT_CH + o] + s1 * Wc[(2 * c + 1) * OUT_CH + o];
    #pragma unroll
    for (int o = 0; o < OUT_CH; ++o) {
        p[o] += __shfl_xor(p[o], 1);
        p[o] += __shfl_xor(p[o], 2);
        p[o] += __shfl_xor(p[o], 4);
        p[o] += __shfl_xor(p[o], 8);
        p[o] += __shfl_xor(p[o], 16);
        p[o] += __shfl_xor(p[o], 32);
    }
    if (c == 0) {
        #pragma unroll
        for (int o = 0; o < OUT_CH; ++o)
            atomicAdd(&out[g * OUT_CH + o], p[o]);
    }
}

// ---------------- launch ----------------
extern "C" void kernel_launch(void* const* d_in, const int* in_sizes, int n_in,
                              void* d_out, int out_size, void* d_ws, size_t ws_size,
                              hipStream_t stream) {
    const float* x     = (const float*)d_in[0];
    const int*   eidx  = (const int*)d_in[1];
    const int*   batch = (const int*)d_in[2];
    const float* W1    = (const float*)d_in[3];
    const float* b1    = (const float*)d_in[4];
    const float* W2    = (const float*)d_in[5];
    const float* b2    = (const float*)d_in[6];
    const float* gamma = (const float*)d_in[7];
    const float* beta  = (const float*)d_in[8];
    const float* mean  = (const float*)d_in[9];
    const float* var   = (const float*)d_in[10];
    const float* Wc    = (const float*)d_in[11];
    const float* bc    = (const float*)d_in[12];
    float* out = (float*)d_out;

    const int* src = eidx;
    const int* dst = eidx + N_EDGES;

    char* w = (char*)d_ws;
    size_t off = 0;
    auto alloc = [&](size_t bytes) { void* p = w + off; off += (bytes + 255) & ~(size_t)255; return p; };
    int*      gcur   = (int*)alloc(NB * 4);
    unsigned* gbuck  = (unsigned*)alloc((size_t)NB * BCAP * 4);
    int*      rowptr = (int*)alloc((N_NODES + 1) * 4);
    ushort_t* esrc   = (ushort_t*)alloc(N_EDGES * 2);
    int*      starts = (int*)alloc((N_GRAPHS + 1) * 4);
    ushort_t* Bh     = (ushort_t*)alloc((size_t)N_NODES * CH * 2);
    ushort_t* Bz     = (ushort_t*)alloc((size_t)N_NODES * CH * 2);
    ushort_t* Wt     = (ushort_t*)alloc((size_t)6 * CH * CH * 2);
    float*    scale  = (float*)alloc(6 * CH * 4);
    float*    shift  = (float*)alloc(6 * CH * 4);
    (void)ws_size; (void)n_in; (void)in_sizes; (void)out_size;

    setup_kernel<<<CB + SB + PB, 256, 0, stream>>>(
        (const float4*)x, (ushort4*)Bh, gcur,
        batch, starts, out, bc,
        W1, W2, Wt, b1, b2, gamma, beta, mean, var, scale, shift);
    bin_kernel<<<(N_EDGES + EPB - 1) / EPB, 256, 0, stream>>>(src, dst, gcur, gbuck);
    place_kernel<<<NB, 256, 0, stream>>>(gcur, gbuck, rowptr, esrc);

    ushort_t* bufA = Bh;
    ushort_t* bufB = Bz;
    for (int i = 0; i < N_LAYERS; ++i) {
        layer_kernel<<<NTILES, 512, 0, stream>>>((const unsigned*)bufA, rowptr, esrc,
                                                 Wt + (size_t)i * CH * CH,
                                                 Wt + (size_t)(3 + i) * CH * CH,
                                                 shift + i * CH,
                                                 scale + (3 + i) * CH,
                                                 shift + (3 + i) * CH,
                                                 bufB);
        ushort_t* tmp = bufA; bufA = bufB; bufB = tmp;
    }

    pool_kernel<<<N_GRAPHS * NSPLIT, 64, 0, stream>>>((const unsigned*)bufA, starts, Wc, out);
}